// Round 2
// baseline (8714.096 us; speedup 1.0000x reference)
//
#include <hip/hip_runtime.h>
#include <cstdint>

#define HIDDEN  128
#define NLAYERS 6
#define NNODES  50000
#define NEDGES  640000

// ---- bf16 <-> f32 helpers (RNE) -------------------------------------------
__device__ __forceinline__ float bf2f(unsigned short u) {
    return __uint_as_float(((unsigned int)u) << 16);
}
__device__ __forceinline__ unsigned short f2bf(float f) {
    unsigned int u = __float_as_uint(f);
    unsigned int r = u + 0x7FFFu + ((u >> 16) & 1u);   // round-nearest-even
    return (unsigned short)(r >> 16);
}

// ---------------------------------------------------------------------------
// Index dtype detection: if edge_index was uploaded as int64, the odd int32
// words (hi words of values < 50000) are all zero. flag=1 -> int32 layout.
// ---------------------------------------------------------------------------
__global__ void detect_kernel(const int* __restrict__ ei, int* __restrict__ flag)
{
    int lane = threadIdx.x;                 // 0..63
    int v = ei[2 * lane + 1];
    unsigned long long b = __ballot(v != 0);
    if (lane == 0) *flag = (b != 0ULL) ? 1 : 0;
}

// Canonicalize to int32 src/dst, clamped into range (fault-proofing).
__global__ void normidx_kernel(const int* __restrict__ ei, const int* __restrict__ flag,
                               int* __restrict__ s32, int* __restrict__ d32)
{
    int e = blockIdx.x * blockDim.x + threadIdx.x;
    if (e >= NEDGES) return;
    int s, d;
    if (*flag) {                            // int32 layout
        s = ei[e];
        d = ei[NEDGES + e];
    } else {                                // int64 layout: lo words
        s = ei[2 * e];
        d = ei[2 * (NEDGES + e)];
    }
    s32[e] = min(max(s, 0), NNODES - 1);
    d32[e] = min(max(d, 0), NNODES - 1);
}

// ---------------------------------------------------------------------------
// Encoder: ef[e][:] = edge_attr[e][0:3] @ enc_w[3][128] + enc_b   (bf16 out)
// ---------------------------------------------------------------------------
__global__ void encode_kernel(const float* __restrict__ ea,
                              const float* __restrict__ w,
                              const float* __restrict__ b,
                              unsigned short* __restrict__ ef)
{
    int idx = blockIdx.x * blockDim.x + threadIdx.x;
    int e = idx >> 5;
    if (e >= NEDGES) return;
    int j = (idx & 31) << 2;
    float a0 = ea[e * 3 + 0], a1 = ea[e * 3 + 1], a2 = ea[e * 3 + 2];
    float4 w0 = *(const float4*)(w + 0 * HIDDEN + j);
    float4 w1 = *(const float4*)(w + 1 * HIDDEN + j);
    float4 w2 = *(const float4*)(w + 2 * HIDDEN + j);
    float4 bb = *(const float4*)(b + j);
    ushort4 o;
    o.x = f2bf(fmaf(a0, w0.x, fmaf(a1, w1.x, fmaf(a2, w2.x, bb.x))));
    o.y = f2bf(fmaf(a0, w0.y, fmaf(a1, w1.y, fmaf(a2, w2.y, bb.y))));
    o.z = f2bf(fmaf(a0, w0.z, fmaf(a1, w1.z, fmaf(a2, w2.z, bb.z))));
    o.w = f2bf(fmaf(a0, w0.w, fmaf(a1, w1.w, fmaf(a2, w2.w, bb.w))));
    *(ushort4*)(ef + (long)e * HIDDEN + j) = o;
}

// ---------------------------------------------------------------------------
// Degree count
// ---------------------------------------------------------------------------
__global__ void count_kernel(const int* __restrict__ dst, float* __restrict__ cnt)
{
    int e = blockIdx.x * blockDim.x + threadIdx.x;
    if (e < NEDGES) atomicAdd(&cnt[dst[e]], 1.0f);
}

// ---------------------------------------------------------------------------
// Fused edge layer:
//   m = relu(concat(x[dst],x[src],ef) @ W1 + b1) @ W2 + b2
//   ef += m (bf16) ;  sums[dst] += m (fp32 atomic)
// Block: 256 threads, tile 64 edges x 128 outputs; 8x4 register acc/thread.
// ---------------------------------------------------------------------------
__global__ __launch_bounds__(256, 3)
void edge_layer_kernel(const float* __restrict__ x,
                       unsigned short* __restrict__ ef,
                       float* __restrict__ sums,
                       const int* __restrict__ src,
                       const int* __restrict__ dst,
                       const float* __restrict__ W1,  // [384][128]
                       const float* __restrict__ b1,
                       const float* __restrict__ W2,  // [128][128]
                       const float* __restrict__ b2)
{
    __shared__ float As[64][17];
    __shared__ float Ws[16][HIDDEN];
    __shared__ float Hs[64][132];
    __shared__ int   sIdx[64][2];

    const int tid = threadIdx.x;
    const long e0 = (long)blockIdx.x * 64;

    if (tid < 64) {
        sIdx[tid][0] = dst[e0 + tid];
        sIdx[tid][1] = src[e0 + tid];
    }
    __syncthreads();

    const int tx = tid & 31;
    const int ty = tid >> 5;

    float acc[8][4];
#pragma unroll
    for (int r = 0; r < 8; ++r)
#pragma unroll
        for (int c = 0; c < 4; ++c) acc[r][c] = 0.0f;

    // ---- GEMM1: K = 384 in 24 chunks of 16 ----
    const int sr = tid >> 2;            // staging row 0..63
    const int sk = (tid & 3) << 2;      // staging col 0,4,8,12
    for (int c = 0; c < 24; ++c) {
        const int s = c >> 3;           // 0: x[dst], 1: x[src], 2: ef
        const int koff = (c & 7) << 4;
        if (s < 2) {
            const float* sp = x + (long)sIdx[sr][s ^ 0] * HIDDEN;  // s=0 dst, s=1 src
            const float* spp = x + (long)sIdx[sr][s] * HIDDEN;
            (void)sp;
            float4 v = *(const float4*)(spp + koff + sk);
            As[sr][sk + 0] = v.x; As[sr][sk + 1] = v.y;
            As[sr][sk + 2] = v.z; As[sr][sk + 3] = v.w;
        } else {
            ushort4 v = *(const ushort4*)(ef + (e0 + sr) * HIDDEN + koff + sk);
            As[sr][sk + 0] = bf2f(v.x); As[sr][sk + 1] = bf2f(v.y);
            As[sr][sk + 2] = bf2f(v.z); As[sr][sk + 3] = bf2f(v.w);
        }
#pragma unroll
        for (int i = 0; i < 2; ++i) {
            int idx = i * 256 + tid;         // 0..511 float4s
            int kk = idx >> 5;
            int j4 = (idx & 31) << 2;
            *(float4*)&Ws[kk][j4] = *(const float4*)(W1 + (long)(c * 16 + kk) * HIDDEN + j4);
        }
        __syncthreads();
#pragma unroll
        for (int kk = 0; kk < 16; ++kk) {
            float4 wv = *(const float4*)&Ws[kk][tx << 2];
            float av[8];
#pragma unroll
            for (int r = 0; r < 8; ++r) av[r] = As[(ty << 3) + r][kk];
#pragma unroll
            for (int r = 0; r < 8; ++r) {
                acc[r][0] = fmaf(av[r], wv.x, acc[r][0]);
                acc[r][1] = fmaf(av[r], wv.y, acc[r][1]);
                acc[r][2] = fmaf(av[r], wv.z, acc[r][2]);
                acc[r][3] = fmaf(av[r], wv.w, acc[r][3]);
            }
        }
        __syncthreads();
    }

    // ---- h = relu(acc + b1) -> Hs ----
    {
        float4 b1v = *(const float4*)(b1 + (tx << 2));
#pragma unroll
        for (int r = 0; r < 8; ++r) {
            float4 h;
            h.x = fmaxf(acc[r][0] + b1v.x, 0.0f);
            h.y = fmaxf(acc[r][1] + b1v.y, 0.0f);
            h.z = fmaxf(acc[r][2] + b1v.z, 0.0f);
            h.w = fmaxf(acc[r][3] + b1v.w, 0.0f);
            *(float4*)&Hs[(ty << 3) + r][tx << 2] = h;
        }
    }
    __syncthreads();

    // ---- GEMM2: K = 128 in 8 chunks of 16, A from Hs ----
#pragma unroll
    for (int r = 0; r < 8; ++r)
#pragma unroll
        for (int c = 0; c < 4; ++c) acc[r][c] = 0.0f;

    for (int c = 0; c < 8; ++c) {
#pragma unroll
        for (int i = 0; i < 2; ++i) {
            int idx = i * 256 + tid;
            int kk = idx >> 5;
            int j4 = (idx & 31) << 2;
            *(float4*)&Ws[kk][j4] = *(const float4*)(W2 + (long)(c * 16 + kk) * HIDDEN + j4);
        }
        __syncthreads();
#pragma unroll
        for (int kk = 0; kk < 16; ++kk) {
            float4 wv = *(const float4*)&Ws[kk][tx << 2];
            float av[8];
#pragma unroll
            for (int r = 0; r < 8; ++r) av[r] = Hs[(ty << 3) + r][(c << 4) + kk];
#pragma unroll
            for (int r = 0; r < 8; ++r) {
                acc[r][0] = fmaf(av[r], wv.x, acc[r][0]);
                acc[r][1] = fmaf(av[r], wv.y, acc[r][1]);
                acc[r][2] = fmaf(av[r], wv.z, acc[r][2]);
                acc[r][3] = fmaf(av[r], wv.w, acc[r][3]);
            }
        }
        __syncthreads();
    }

    // ---- epilogue: m = acc + b2 ; ef += m (bf16) ; sums[dst] += m ----
    {
        float4 b2v = *(const float4*)(b2 + (tx << 2));
        const int j = tx << 2;
#pragma unroll
        for (int r = 0; r < 8; ++r) {
            const int row = (ty << 3) + r;
            const long e = e0 + row;
            const int d = sIdx[row][0];
            float mx = acc[r][0] + b2v.x;
            float my = acc[r][1] + b2v.y;
            float mz = acc[r][2] + b2v.z;
            float mw = acc[r][3] + b2v.w;
            unsigned short* ep = ef + e * HIDDEN + j;
            ushort4 eo = *(ushort4*)ep;
            ushort4 en;
            en.x = f2bf(bf2f(eo.x) + mx);
            en.y = f2bf(bf2f(eo.y) + my);
            en.z = f2bf(bf2f(eo.z) + mz);
            en.w = f2bf(bf2f(eo.w) + mw);
            *(ushort4*)ep = en;
            float* sp = sums + (long)d * HIDDEN + j;
            atomicAdd(sp + 0, mx);
            atomicAdd(sp + 1, my);
            atomicAdd(sp + 2, mz);
            atomicAdd(sp + 3, mw);
        }
    }
}

// ---------------------------------------------------------------------------
// Fused node layer:
//   aggr = sums / max(cnt,1)
//   x += relu(concat(x,aggr) @ W1 + b1) @ W2 + b2
// ---------------------------------------------------------------------------
__global__ __launch_bounds__(256, 3)
void node_layer_kernel(float* __restrict__ x,
                       const float* __restrict__ sums,
                       const float* __restrict__ cnt,
                       const float* __restrict__ W1,  // [256][128]
                       const float* __restrict__ b1,
                       const float* __restrict__ W2,  // [128][128]
                       const float* __restrict__ b2)
{
    __shared__ float As[64][17];
    __shared__ float Ws[16][HIDDEN];
    __shared__ float Hs[64][132];
    __shared__ float cInv[64];

    const int tid = threadIdx.x;
    const long n0 = (long)blockIdx.x * 64;

    if (tid < 64) {
        long n = n0 + tid;
        cInv[tid] = (n < NNODES) ? 1.0f / fmaxf(cnt[n], 1.0f) : 0.0f;
    }
    __syncthreads();

    const int tx = tid & 31;
    const int ty = tid >> 5;

    float acc[8][4];
#pragma unroll
    for (int r = 0; r < 8; ++r)
#pragma unroll
        for (int c = 0; c < 4; ++c) acc[r][c] = 0.0f;

    const int sr = tid >> 2;
    const int sk = (tid & 3) << 2;
    long nClamp = n0 + sr; if (nClamp >= NNODES) nClamp = NNODES - 1;

    // ---- GEMM1: K = 256 in 16 chunks of 16 ----
    for (int c = 0; c < 16; ++c) {
        const int koff = (c & 7) << 4;
        {
            float4 v;
            if (c < 8) {
                v = *(const float4*)(x + nClamp * HIDDEN + koff + sk);
            } else {
                v = *(const float4*)(sums + nClamp * HIDDEN + koff + sk);
                float ci = cInv[sr];
                v.x *= ci; v.y *= ci; v.z *= ci; v.w *= ci;
            }
            As[sr][sk + 0] = v.x; As[sr][sk + 1] = v.y;
            As[sr][sk + 2] = v.z; As[sr][sk + 3] = v.w;
        }
#pragma unroll
        for (int i = 0; i < 2; ++i) {
            int idx = i * 256 + tid;
            int kk = idx >> 5;
            int j4 = (idx & 31) << 2;
            *(float4*)&Ws[kk][j4] = *(const float4*)(W1 + (long)(c * 16 + kk) * HIDDEN + j4);
        }
        __syncthreads();
#pragma unroll
        for (int kk = 0; kk < 16; ++kk) {
            float4 wv = *(const float4*)&Ws[kk][tx << 2];
            float av[8];
#pragma unroll
            for (int r = 0; r < 8; ++r) av[r] = As[(ty << 3) + r][kk];
#pragma unroll
            for (int r = 0; r < 8; ++r) {
                acc[r][0] = fmaf(av[r], wv.x, acc[r][0]);
                acc[r][1] = fmaf(av[r], wv.y, acc[r][1]);
                acc[r][2] = fmaf(av[r], wv.z, acc[r][2]);
                acc[r][3] = fmaf(av[r], wv.w, acc[r][3]);
            }
        }
        __syncthreads();
    }

    {
        float4 b1v = *(const float4*)(b1 + (tx << 2));
#pragma unroll
        for (int r = 0; r < 8; ++r) {
            float4 h;
            h.x = fmaxf(acc[r][0] + b1v.x, 0.0f);
            h.y = fmaxf(acc[r][1] + b1v.y, 0.0f);
            h.z = fmaxf(acc[r][2] + b1v.z, 0.0f);
            h.w = fmaxf(acc[r][3] + b1v.w, 0.0f);
            *(float4*)&Hs[(ty << 3) + r][tx << 2] = h;
        }
    }
    __syncthreads();

#pragma unroll
    for (int r = 0; r < 8; ++r)
#pragma unroll
        for (int c = 0; c < 4; ++c) acc[r][c] = 0.0f;

    for (int c = 0; c < 8; ++c) {
#pragma unroll
        for (int i = 0; i < 2; ++i) {
            int idx = i * 256 + tid;
            int kk = idx >> 5;
            int j4 = (idx & 31) << 2;
            *(float4*)&Ws[kk][j4] = *(const float4*)(W2 + (long)(c * 16 + kk) * HIDDEN + j4);
        }
        __syncthreads();
#pragma unroll
        for (int kk = 0; kk < 16; ++kk) {
            float4 wv = *(const float4*)&Ws[kk][tx << 2];
            float av[8];
#pragma unroll
            for (int r = 0; r < 8; ++r) av[r] = Hs[(ty << 3) + r][(c << 4) + kk];
#pragma unroll
            for (int r = 0; r < 8; ++r) {
                acc[r][0] = fmaf(av[r], wv.x, acc[r][0]);
                acc[r][1] = fmaf(av[r], wv.y, acc[r][1]);
                acc[r][2] = fmaf(av[r], wv.z, acc[r][2]);
                acc[r][3] = fmaf(av[r], wv.w, acc[r][3]);
            }
        }
        __syncthreads();
    }

    {
        float4 b2v = *(const float4*)(b2 + (tx << 2));
        const int j = tx << 2;
#pragma unroll
        for (int r = 0; r < 8; ++r) {
            const long n = n0 + (ty << 3) + r;
            if (n < NNODES) {
                float4 xv = *(float4*)(x + n * HIDDEN + j);
                xv.x += acc[r][0] + b2v.x;
                xv.y += acc[r][1] + b2v.y;
                xv.z += acc[r][2] + b2v.z;
                xv.w += acc[r][3] + b2v.w;
                *(float4*)(x + n * HIDDEN + j) = xv;
            }
        }
    }
}

// ---------------------------------------------------------------------------
// Decoder + row L2-normalize. One wave (64 lanes) per node.
// ---------------------------------------------------------------------------
__global__ void decode_kernel(const float* __restrict__ x,
                              const float* __restrict__ w,   // [128][3]
                              const float* __restrict__ b,   // [3]
                              float* __restrict__ out)
{
    int gid = blockIdx.x * blockDim.x + threadIdx.x;
    int node = gid >> 6;
    int lane = threadIdx.x & 63;
    if (node >= NNODES) return;
    float a0 = 0.f, a1 = 0.f, a2 = 0.f;
#pragma unroll
    for (int k = lane; k < HIDDEN; k += 64) {
        float xv = x[(long)node * HIDDEN + k];
        a0 = fmaf(xv, w[k * 3 + 0], a0);
        a1 = fmaf(xv, w[k * 3 + 1], a1);
        a2 = fmaf(xv, w[k * 3 + 2], a2);
    }
#pragma unroll
    for (int off = 32; off > 0; off >>= 1) {
        a0 += __shfl_down(a0, off);
        a1 += __shfl_down(a1, off);
        a2 += __shfl_down(a2, off);
    }
    if (lane == 0) {
        a0 += b[0]; a1 += b[1]; a2 += b[2];
        float nrm = sqrtf(a0 * a0 + a1 * a1 + a2 * a2);
        float inv = 1.0f / fmaxf(nrm, 1e-12f);
        out[(long)node * 3 + 0] = a0 * inv;
        out[(long)node * 3 + 1] = a1 * inv;
        out[(long)node * 3 + 2] = a2 * inv;
    }
}

// ---------------------------------------------------------------------------
extern "C" void kernel_launch(void* const* d_in, const int* in_sizes, int n_in,
                              void* d_out, int out_size, void* d_ws, size_t ws_size,
                              hipStream_t stream)
{
    const float* edge_attr = (const float*)d_in[1];
    const int*   ei        = (const int*)d_in[2];
    const float* enc_w     = (const float*)d_in[3];
    const float* enc_b     = (const float*)d_in[4];
    const float* dec_w     = (const float*)d_in[5];
    const float* dec_b     = (const float*)d_in[6];
    const float* edge_w1   = (const float*)d_in[7];
    const float* edge_b1   = (const float*)d_in[8];
    const float* edge_w2   = (const float*)d_in[9];
    const float* edge_b2   = (const float*)d_in[10];
    const float* node_w1   = (const float*)d_in[11];
    const float* node_b1   = (const float*)d_in[12];
    const float* node_w2   = (const float*)d_in[13];
    const float* node_b2   = (const float*)d_in[14];

    // workspace layout (bytes):
    //   ef_bf16 : 0                 .. 163,840,000
    //   x       : 163,840,000      .. 189,440,000
    //   sums    : 189,440,000      .. 215,040,000
    //   cnt     : 215,040,000      .. 215,240,192
    //   src32   : 215,240,192      .. 217,800,192
    //   dst32   : 217,800,192      .. 220,360,192
    //   flag    : 220,360,192      .. +4            (total ~210 MiB)
    char* ws = (char*)d_ws;
    unsigned short* ef  = (unsigned short*)(ws);
    float* x    = (float*)(ws + 163840000L);
    float* sums = (float*)(ws + 189440000L);
    float* cnt  = (float*)(ws + 215040000L);
    int*   src  = (int*)  (ws + 215240192L);
    int*   dst  = (int*)  (ws + 217800192L);
    int*   flag = (int*)  (ws + 220360192L);

    float* out = (float*)d_out;

    // zero-init state (ws is poisoned before every call)
    hipMemsetAsync(x, 0, (size_t)NNODES * HIDDEN * sizeof(float), stream);
    hipMemsetAsync(cnt, 0, (size_t)50048 * sizeof(float), stream);

    detect_kernel<<<1, 64, 0, stream>>>(ei, flag);
    normidx_kernel<<<(NEDGES + 255) / 256, 256, 0, stream>>>(ei, flag, src, dst);
    count_kernel<<<(NEDGES + 255) / 256, 256, 0, stream>>>(dst, cnt);
    encode_kernel<<<(NEDGES * 32 + 255) / 256, 256, 0, stream>>>(edge_attr, enc_w, enc_b, ef);

    for (int l = 0; l < NLAYERS; ++l) {
        hipMemsetAsync(sums, 0, (size_t)NNODES * HIDDEN * sizeof(float), stream);
        edge_layer_kernel<<<NEDGES / 64, 256, 0, stream>>>(
            x, ef, sums, src, dst,
            edge_w1 + (long)l * 384 * HIDDEN, edge_b1 + (long)l * HIDDEN,
            edge_w2 + (long)l * HIDDEN * HIDDEN, edge_b2 + (long)l * HIDDEN);
        node_layer_kernel<<<(NNODES + 63) / 64, 256, 0, stream>>>(
            x, sums, cnt,
            node_w1 + (long)l * 256 * HIDDEN, node_b1 + (long)l * HIDDEN,
            node_w2 + (long)l * HIDDEN * HIDDEN, node_b2 + (long)l * HIDDEN);
    }

    decode_kernel<<<(NNODES * 64 + 255) / 256, 256, 0, stream>>>(x, dec_w, dec_b, out);
}